// Round 1
// baseline (910.250 us; speedup 1.0000x reference)
//
#include <hip/hip_runtime.h>
#include <hip/hip_bf16.h>

// ---------------------------------------------------------------------------
// UserTower: algebraically-restructured pipeline.
//   prep:  WkT[h][e] = sum_d Wk[e, h*32+d]; bkSum[h]; biasS[kd] = 4*sum_h bv[h*32+kd]
//   main (1 block per batch row b, 256 threads):
//     scale[j] = (u·Wq[:,j] + bq[j]) / sqrt(32)
//     ksum[n][h] = it_n·WkT[h] + bkSum[h]
//     m, invden per (h,qd) via per-head max/min of ksum
//     W4[n][hq] = sum_g softmax-weight(h, g*8+qm, n)      (hq = h*8+qm)
//     A[hq][e]  = sum_n W4[n][hq] * it[n][e]              (fp32 regs -> bf16 LDS)
//     T_h[qm][kd] = sum_e A[h*8+qm][e] * Wv[e][h*32+kd]
//     S[c] = sum_h T + biasS[kd];  user_rep[e'] = S·Wo[:,e'] + 32*bo[e']
//   mlp (8 rows per block): out = relu([u|ur]@W1+b1)@W2+b2
// ---------------------------------------------------------------------------

constexpr int BATCH   = 2048;
constexpr int N_ITEMS = 200;
constexpr int EMBD    = 256;

static __device__ __forceinline__ unsigned short f32_to_bf16(float f) {
    union { float f; unsigned int u; } v; v.f = f;
    unsigned int r = v.u + 0x7fffu + ((v.u >> 16) & 1u);   // RNE
    return (unsigned short)(r >> 16);
}
static __device__ __forceinline__ float bf16_to_f32(unsigned short h) {
    union { unsigned int u; float f; } v; v.u = ((unsigned int)h) << 16;
    return v.f;
}

__global__ void ut_prep(const float* __restrict__ Wk,
                        const float* __restrict__ bk,
                        const float* __restrict__ bv,
                        float* __restrict__ ws)
{
    if (blockIdx.x < 8) {
        int g = blockIdx.x * 256 + threadIdx.x;   // (e,h) pair
        int e = g >> 3, h = g & 7;
        float s = 0.f;
        #pragma unroll
        for (int d = 0; d < 32; ++d) s += Wk[e * 256 + h * 32 + d];
        ws[h * 256 + e] = s;                      // WkT[h][e]
    } else {
        int t = threadIdx.x;
        if (t < 32) {
            float s = 0.f;
            #pragma unroll
            for (int h = 0; h < 8; ++h) s += bv[h * 32 + t];
            ws[2056 + t] = 4.f * s;               // biasS[kd]
        } else if (t < 40) {
            int h = t - 32;
            float s = 0.f;
            #pragma unroll
            for (int d = 0; d < 32; ++d) s += bk[h * 32 + d];
            ws[2048 + h] = s;                     // bkSum[h]
        }
    }
}

__global__ __launch_bounds__(256) void ut_main(
    const int*   __restrict__ user_id,
    const int*   __restrict__ item_ids,
    const float* __restrict__ user_table,
    const float* __restrict__ item_table,
    const float* __restrict__ Wq, const float* __restrict__ bq,
    const float* __restrict__ Wv,
    const float* __restrict__ Wo, const float* __restrict__ bo,
    const float* __restrict__ prep,       // WkT(2048) | bkSum(8) | biasS(32)
    float*       __restrict__ user_rep)
{
    // region1 overlays: [phase C] WkT 8KB -> [D2..E] W4[n][64] 51.2KB
    //                   -> [E-end..F] A bf16 [256][stride 72] 36.9KB + T 8KB @36864
    __shared__ __align__(16) float region1[12800];
    __shared__ float ksumL[N_ITEMS * 8];
    __shared__ int   idsL[N_ITEMS];
    __shared__ float uL[EMBD];
    __shared__ float scaleL[EMBD];
    __shared__ float mL[EMBD];
    __shared__ float invdL[EMBD];
    __shared__ float maxkL[8], minkL[8], bkSumL[8];
    __shared__ float biasSL[32];
    __shared__ float SL[EMBD];

    const int b    = blockIdx.x;
    const int t    = threadIdx.x;
    const int lane = t & 63;
    const int wid  = t >> 6;

    if (t < N_ITEMS) idsL[t] = item_ids[b * N_ITEMS + t];
    uL[t] = user_table[(long)user_id[b] * EMBD + t];
    #pragma unroll
    for (int i = 0; i < 8; ++i) region1[i * 256 + t] = prep[i * 256 + t];
    if (t < 8)  bkSumL[t] = prep[2048 + t];
    if (t < 32) biasSL[t] = prep[2056 + t];
    __syncthreads();

    // Phase B: scale[j] = (bq[j] + u·Wq[:,j]) / sqrt(32)   (coalesced Wq cols)
    {
        float acc = bq[t];
        for (int e = 0; e < EMBD; ++e) acc = fmaf(uL[e], Wq[e * EMBD + t], acc);
        scaleL[t] = acc * 0.17677669529663687f;
    }

    // Phase C: ksum[n][h] = it_n·WkT[h] + bkSum[h]; wave handles n ≡ wid (mod 4)
    {
        const float4* wkt4 = (const float4*)region1;     // [8][64] float4
        for (int n = wid; n < N_ITEMS; n += 4) {
            const float4* row = (const float4*)(item_table + (long)idsL[n] * EMBD);
            float4 x = row[lane];                         // e = 4*lane..4*lane+3
            float p[8];
            #pragma unroll
            for (int h = 0; h < 8; ++h) {
                float4 wk = wkt4[h * 64 + lane];
                p[h] = x.x * wk.x + x.y * wk.y + x.z * wk.z + x.w * wk.w;
            }
            #pragma unroll
            for (int h = 0; h < 8; ++h) {
                float v = p[h];
                v += __shfl_xor(v, 1);
                v += __shfl_xor(v, 2);
                v += __shfl_xor(v, 4);
                v += __shfl_xor(v, 8);
                v += __shfl_xor(v, 16);
                v += __shfl_xor(v, 32);
                p[h] = v;
            }
            if (lane == 0) {
                #pragma unroll
                for (int h = 0; h < 8; ++h) ksumL[n * 8 + h] = p[h] + bkSumL[h];
            }
        }
    }
    __syncthreads();

    // Phase C2: per-head max / min of ksum (for exact softmax max via sign of scale)
    if (t < 64) {
        int h = t >> 3, seg = t & 7;
        float mx = -3.4e38f, mn = 3.4e38f;
        for (int n = seg * 25; n < seg * 25 + 25; ++n) {
            float s = ksumL[n * 8 + h];
            mx = fmaxf(mx, s); mn = fminf(mn, s);
        }
        mx = fmaxf(mx, __shfl_xor(mx, 1)); mn = fminf(mn, __shfl_xor(mn, 1));
        mx = fmaxf(mx, __shfl_xor(mx, 2)); mn = fminf(mn, __shfl_xor(mn, 2));
        mx = fmaxf(mx, __shfl_xor(mx, 4)); mn = fminf(mn, __shfl_xor(mn, 4));
        if (seg == 0) { maxkL[h] = mx; minkL[h] = mn; }
    }
    __syncthreads();

    // Phase D1: thread t = (h,qd): softmax max + 1/denominator
    {
        int h = t >> 5;
        float sc  = scaleL[t];
        float m   = (sc >= 0.f) ? sc * maxkL[h] : sc * minkL[h];
        float den = 0.f;
        for (int n = 0; n < N_ITEMS; ++n) den += __expf(sc * ksumL[n * 8 + h] - m);
        mL[t]    = m;
        invdL[t] = 1.f / den;
    }
    __syncthreads();

    // Phase D2: W4[n][hq] = sum_g exp(scale·s - m)·invden   (hq = h*8+qm)
    {
        int hq = t >> 2, nb0 = t & 3;
        int h = hq >> 3, qm = hq & 7;
        float sc[4], mm[4], iv[4];
        #pragma unroll
        for (int g = 0; g < 4; ++g) {
            int qi = h * 32 + g * 8 + qm;
            sc[g] = scaleL[qi]; mm[g] = mL[qi]; iv[g] = invdL[qi];
        }
        for (int n = nb0; n < N_ITEMS; n += 4) {
            float s = ksumL[n * 8 + h];
            float w = 0.f;
            #pragma unroll
            for (int g = 0; g < 4; ++g) w += __expf(fmaf(sc[g], s, -mm[g])) * iv[g];
            region1[n * 64 + hq] = w;
        }
    }
    __syncthreads();

    // Phase E: A[hq][col=t] = sum_n W4[n][hq] * it[n][t]   (64 fp32 accs/thread)
    float accA[64];
    #pragma unroll
    for (int i = 0; i < 64; ++i) accA[i] = 0.f;
    {
        const float4* w44 = (const float4*)region1;
        for (int n = 0; n < N_ITEMS; ++n) {
            float x = item_table[(long)idsL[n] * EMBD + t];   // L2 re-hit from phase C
            #pragma unroll
            for (int i = 0; i < 16; ++i) {
                float4 w = w44[n * 16 + i];                    // LDS broadcast
                accA[4 * i + 0] = fmaf(w.x, x, accA[4 * i + 0]);
                accA[4 * i + 1] = fmaf(w.y, x, accA[4 * i + 1]);
                accA[4 * i + 2] = fmaf(w.z, x, accA[4 * i + 2]);
                accA[4 * i + 3] = fmaf(w.w, x, accA[4 * i + 3]);
            }
        }
    }
    __syncthreads();       // all waves finished READING W4 before overwrite
    {
        unsigned int* Arow = (unsigned int*)((unsigned short*)region1 + t * 72);
        #pragma unroll
        for (int i = 0; i < 32; ++i) {
            unsigned int pk = (unsigned int)f32_to_bf16(accA[2 * i])
                            | ((unsigned int)f32_to_bf16(accA[2 * i + 1]) << 16);
            Arow[i] = pk;  // A[e=t][hq], row stride 72 shorts (144B, 16B-aligned)
        }
    }
    __syncthreads();

    // Phase F: T_h[qm][kd] = sum_e A[e][h*8+qm] * Wv[e][h*32+kd]   (t = h*32+kd)
    {
        int h = t >> 5;
        float a8[8];
        #pragma unroll
        for (int i = 0; i < 8; ++i) a8[i] = 0.f;
        const unsigned short* A = (const unsigned short*)region1;
        for (int e = 0; e < EMBD; ++e) {
            float wvv = Wv[e * EMBD + t];                       // fully coalesced
            uint4 raw = *(const uint4*)(A + e * 72 + h * 8);    // 8 bf16, b128 read
            a8[0] = fmaf(bf16_to_f32((unsigned short)(raw.x & 0xffffu)), wvv, a8[0]);
            a8[1] = fmaf(bf16_to_f32((unsigned short)(raw.x >> 16)),     wvv, a8[1]);
            a8[2] = fmaf(bf16_to_f32((unsigned short)(raw.y & 0xffffu)), wvv, a8[2]);
            a8[3] = fmaf(bf16_to_f32((unsigned short)(raw.y >> 16)),     wvv, a8[3]);
            a8[4] = fmaf(bf16_to_f32((unsigned short)(raw.z & 0xffffu)), wvv, a8[4]);
            a8[5] = fmaf(bf16_to_f32((unsigned short)(raw.z >> 16)),     wvv, a8[5]);
            a8[6] = fmaf(bf16_to_f32((unsigned short)(raw.w & 0xffffu)), wvv, a8[6]);
            a8[7] = fmaf(bf16_to_f32((unsigned short)(raw.w >> 16)),     wvv, a8[7]);
        }
        float* T = (float*)((char*)region1 + 36864);
        #pragma unroll
        for (int qm = 0; qm < 8; ++qm) T[h * 256 + qm * 32 + (t & 31)] = a8[qm];
    }
    __syncthreads();

    // Phase G: S[c] = biasS[kd] + sum_h T ; user_rep = S·Wo + 32*bo
    {
        const float* T = (const float*)((char*)region1 + 36864);
        float s = biasSL[t & 31];
        #pragma unroll
        for (int h = 0; h < 8; ++h) s += T[h * 256 + t];
        SL[t] = s;
    }
    __syncthreads();
    {
        float acc = 32.f * bo[t];
        for (int c = 0; c < EMBD; ++c) acc = fmaf(SL[c], Wo[c * EMBD + t], acc);
        user_rep[(long)b * EMBD + t] = acc;
    }
}

__global__ __launch_bounds__(256) void ut_mlp(
    const int*   __restrict__ user_id,
    const float* __restrict__ user_table,
    const float* __restrict__ user_rep,
    const float* __restrict__ W1, const float* __restrict__ b1,
    const float* __restrict__ W2, const float* __restrict__ b2,
    float*       __restrict__ out)
{
    __shared__ float X[8 * 512];
    __shared__ float Hs[8 * 1024];
    const int t  = threadIdx.x;
    const int b0 = blockIdx.x * 8;

    #pragma unroll
    for (int r = 0; r < 8; ++r) {
        X[r * 512 + t]       = user_table[(long)user_id[b0 + r] * EMBD + t];
        X[r * 512 + 256 + t] = user_rep[(long)(b0 + r) * EMBD + t];
    }
    __syncthreads();

    float acc[8][4];
    #pragma unroll
    for (int r = 0; r < 8; ++r) {
        #pragma unroll
        for (int k2 = 0; k2 < 4; ++k2) acc[r][k2] = b1[t + 256 * k2];
    }
    for (int e = 0; e < 512; ++e) {
        float w0 = W1[e * 1024 + t];
        float w1 = W1[e * 1024 + t + 256];
        float w2 = W1[e * 1024 + t + 512];
        float w3 = W1[e * 1024 + t + 768];
        #pragma unroll
        for (int r = 0; r < 8; ++r) {
            float x = X[r * 512 + e];
            acc[r][0] = fmaf(x, w0, acc[r][0]);
            acc[r][1] = fmaf(x, w1, acc[r][1]);
            acc[r][2] = fmaf(x, w2, acc[r][2]);
            acc[r][3] = fmaf(x, w3, acc[r][3]);
        }
    }
    #pragma unroll
    for (int r = 0; r < 8; ++r) {
        #pragma unroll
        for (int k2 = 0; k2 < 4; ++k2)
            Hs[r * 1024 + t + 256 * k2] = fmaxf(acc[r][k2], 0.f);
    }
    __syncthreads();

    float o[8];
    #pragma unroll
    for (int r = 0; r < 8; ++r) o[r] = b2[t];
    for (int kk = 0; kk < 1024; ++kk) {
        float w = W2[kk * 256 + t];
        #pragma unroll
        for (int r = 0; r < 8; ++r) o[r] = fmaf(Hs[r * 1024 + kk], w, o[r]);
    }
    #pragma unroll
    for (int r = 0; r < 8; ++r) out[(long)(b0 + r) * EMBD + t] = o[r];
}

extern "C" void kernel_launch(void* const* d_in, const int* in_sizes, int n_in,
                              void* d_out, int out_size, void* d_ws, size_t ws_size,
                              hipStream_t stream)
{
    (void)in_sizes; (void)n_in; (void)out_size; (void)ws_size;
    const int*   user_id    = (const int*)d_in[0];
    const int*   item_ids   = (const int*)d_in[1];
    const float* user_table = (const float*)d_in[2];
    const float* item_table = (const float*)d_in[3];
    const float* Wq = (const float*)d_in[4];
    const float* bq = (const float*)d_in[5];
    const float* Wk = (const float*)d_in[6];
    const float* bk = (const float*)d_in[7];
    const float* Wv = (const float*)d_in[8];
    const float* bv = (const float*)d_in[9];
    const float* Wo = (const float*)d_in[10];
    const float* bo = (const float*)d_in[11];
    const float* W1 = (const float*)d_in[12];
    const float* b1 = (const float*)d_in[13];
    const float* W2 = (const float*)d_in[14];
    const float* b2 = (const float*)d_in[15];

    float* ws       = (float*)d_ws;
    float* user_rep = ws + 4096;     // [BATCH][EMBD] fp32

    ut_prep<<<9, 256, 0, stream>>>(Wk, bk, bv, ws);
    ut_main<<<BATCH, 256, 0, stream>>>(user_id, item_ids, user_table, item_table,
                                       Wq, bq, Wv, Wo, bo, ws, user_rep);
    ut_mlp<<<BATCH / 8, 256, 0, stream>>>(user_id, user_table, user_rep,
                                          W1, b1, W2, b2, (float*)d_out);
}

// Round 2
// 414.194 us; speedup vs baseline: 2.1976x; 2.1976x over previous
//
#include <hip/hip_runtime.h>
#include <hip/hip_bf16.h>

// ---------------------------------------------------------------------------
// UserTower, MFMA restructure.
// Key algebra (unchanged from r1): ksum[n][h]=it_n·WkT[h]+bkSum[h];
// W4[hq][n]=sum_g softmaxw(h,g*8+qm,n); S[qm*32+kd]=sum_h (W4_h·IT·Wv_h)+biasS.
// New: reassociate W4·(IT·Wv): per 32-item chunk, M=IT_chunk·Wv via MFMA
// (A=staged chunk bf16 LDS, B=WvT bf16 VGPR frags), M written transposed
// (wave-private Mt rows), then T+=W4frag·Mt via MFMA with W4 built in-register.
// MFMA frag model (16x16x32 bf16): A lane l: [m=l&15][k=8*(l>>4)+j];
// B lane l: [k=8*(l>>4)+j][n=l&15]; D lane l: [row=4*(l>>4)+reg][col=l&15].
// ---------------------------------------------------------------------------

typedef __attribute__((ext_vector_type(8))) short bf16x8;
typedef __attribute__((ext_vector_type(4))) float f32x4;

constexpr int BATCH = 2048;
constexpr int NIT   = 200;
constexpr int EMBD  = 256;
constexpr int NC    = 7;          // ceil(200/32)

// ws byte offsets
constexpr int WKT_OFF  = 0;        // ushort[16][256]  (rows 8..15 zero)
constexpr int WVT_OFF  = 8192;     // ushort[256][256] WvT[c][e] = Wv[e][c]
constexpr int SCL_OFF  = 139264;   // f32 bkSum[8] then biasS[32]
constexpr int UREP_OFF = 147456;   // f32[2048][256]

static __device__ __forceinline__ unsigned short f2b(float f) {
    union { float f; unsigned u; } v; v.f = f;
    unsigned r = v.u + 0x7fffu + ((v.u >> 16) & 1u);   // RNE
    return (unsigned short)(r >> 16);
}
static __device__ __forceinline__ unsigned pack2(float a, float b) {
    return (unsigned)f2b(a) | ((unsigned)f2b(b) << 16);
}

__global__ void ut_prep(const float* __restrict__ Wk,
                        const float* __restrict__ bk,
                        const float* __restrict__ bv,
                        const float* __restrict__ Wv,
                        void* wsv)
{
    unsigned short* wkt = (unsigned short*)((char*)wsv + WKT_OFF);
    unsigned short* wvt = (unsigned short*)((char*)wsv + WVT_OFF);
    float* bks  = (float*)((char*)wsv + SCL_OFF);
    float* bias = bks + 8;
    int bid = blockIdx.x, t = threadIdx.x;
    if (bid < 256) {
        int e0 = bid;                               // WvT[c=t][e0] = Wv[e0][c]
        wvt[t * 256 + e0] = f2b(Wv[e0 * 256 + t]);
    } else if (bid < 272) {
        int r = bid - 256;                          // WkT bf16 [16][256]
        float s = 0.f;
        if (r < 8) {
            #pragma unroll
            for (int d = 0; d < 32; ++d) s += Wk[t * 256 + r * 32 + d];
            wkt[r * 256 + t] = f2b(s);
        } else {
            wkt[r * 256 + t] = 0;
        }
    } else {
        if (t < 32) {
            float s = 0.f;
            #pragma unroll
            for (int h = 0; h < 8; ++h) s += bv[h * 32 + t];
            bias[t] = 4.f * s;
        } else if (t < 40) {
            int h = t - 32;
            float s = 0.f;
            #pragma unroll
            for (int d = 0; d < 32; ++d) s += bk[h * 32 + d];
            bks[h] = s;
        }
    }
}

static __device__ __forceinline__ void stage_load(float4* sx, const int* idsL,
        const float* __restrict__ item_table, int c, int snl, int seb)
{
    int gi = c * 32 + snl;
    if (gi < NIT) {
        const float* src = item_table + (long)idsL[gi] * EMBD + seb;
        #pragma unroll
        for (int i = 0; i < 8; ++i) sx[i] = *(const float4*)(src + 32 * i);
    } else {
        #pragma unroll
        for (int i = 0; i < 8; ++i) sx[i] = make_float4(0.f, 0.f, 0.f, 0.f);
    }
}
static __device__ __forceinline__ void stage_write(const float4* sx,
        unsigned short* dst0)
{
    #pragma unroll
    for (int i = 0; i < 8; ++i) {
        uint2 p; p.x = pack2(sx[i].x, sx[i].y); p.y = pack2(sx[i].z, sx[i].w);
        *(uint2*)(dst0 + 32 * i) = p;
    }
}

__global__ __launch_bounds__(256, 2) void ut_main(
    const int*   __restrict__ user_id,
    const int*   __restrict__ item_ids,
    const float* __restrict__ user_table,
    const float* __restrict__ item_table,
    const float* __restrict__ Wq, const float* __restrict__ bq,
    const float* __restrict__ Wo, const float* __restrict__ bo,
    const void*  __restrict__ wsv,
    float*       __restrict__ user_rep)
{
    // itb: double-buffered 32-item chunk, [32][264] bf16 (stride 264 for banks)
    __shared__ __align__(16) unsigned short itb[2][32 * 264];       // 33792 B
    // mtRaw: Mt [256][40] bf16 (20480 B) during pass2; T3 f32[2048] at end
    __shared__ __align__(16) unsigned char mtRaw[20480];
    __shared__ float ksumL[224 * 8];                                 // 7168 B
    __shared__ float uL[EMBD], scaleL[EMBD], mL[EMBD], invdL[EMBD];
    __shared__ int   idsL[NIT];
    __shared__ float maxkL[8], minkL[8], bkSumL[8], biasSL[32];
    __shared__ float SL[EMBD];

    const int b = blockIdx.x, t = threadIdx.x;
    const int lane = t & 63, w = t >> 6;
    const int r16 = lane & 15, g4 = lane >> 4;

    const unsigned short* wkt = (const unsigned short*)((const char*)wsv + WKT_OFF);
    const unsigned short* wvt = (const unsigned short*)((const char*)wsv + WVT_OFF);
    const float* bks  = (const float*)((const char*)wsv + SCL_OFF);
    const float* bias = bks + 8;

    if (t < NIT) idsL[t] = item_ids[b * NIT + t];
    uL[t] = user_table[(long)user_id[b] * EMBD + t];
    if (t < 8)  bkSumL[t] = bks[t];
    if (t < 32) biasSL[t] = bias[t];
    __syncthreads();

    const int snl = t >> 3;           // staged item 0..31
    const int seb = (t & 7) * 4;      // e offset within row
    float4 sx[8];

    // WkT B-frags (pass 1 only): lane l holds WkT[h=r16][e = ks*32 + 8*g4 + j]
    bf16x8 wkf[8];
    #pragma unroll
    for (int ks = 0; ks < 8; ++ks)
        wkf[ks] = *(const bf16x8*)(wkt + r16 * 256 + ks * 32 + g4 * 8);

    // ---------------- pass 1: ksum via MFMA ----------------
    stage_load(sx, idsL, item_table, 0, snl, seb);
    stage_write(sx, &itb[0][snl * 264 + seb]);
    __syncthreads();
    int cur = 0;
    for (int c = 0; c < NC; ++c) {
        if (c + 1 < NC) stage_load(sx, idsL, item_table, c + 1, snl, seb);
        if (w < 2) {                                   // item-tile w of chunk
            f32x4 ka = {0.f, 0.f, 0.f, 0.f};
            #pragma unroll
            for (int ks = 0; ks < 8; ++ks) {
                bf16x8 a = *(const bf16x8*)(&itb[cur][(16 * w + r16) * 264 + ks * 32 + g4 * 8]);
                ka = __builtin_amdgcn_mfma_f32_16x16x32_bf16(a, wkf[ks], ka, 0, 0, 0);
            }
            if (r16 < 8) {                              // D: row=item, col=h
                int h = r16;
                #pragma unroll
                for (int reg = 0; reg < 4; ++reg) {
                    int n = c * 32 + 16 * w + 4 * g4 + reg;
                    ksumL[n * 8 + h] = ka[reg] + bkSumL[h];
                }
            }
        }
        if (c + 1 < NC) stage_write(sx, &itb[cur ^ 1][snl * 264 + seb]);
        __syncthreads();
        cur ^= 1;
    }

    // early-issue pass-2 chunk 0 (hides HBM latency under B/C2/D1)
    stage_load(sx, idsL, item_table, 0, snl, seb);

    // WvT B-frags (resident for pass 2): wave w owns c = 64w + 16ct + r16
    bf16x8 wvf[4][8];
    #pragma unroll
    for (int ct = 0; ct < 4; ++ct) {
        const unsigned short* base = wvt + (64 * w + 16 * ct + r16) * 256;
        #pragma unroll
        for (int ks = 0; ks < 8; ++ks)
            wvf[ct][ks] = *(const bf16x8*)(base + ks * 32 + g4 * 8);
    }

    // Phase B: scale[j] = (bq[j] + u·Wq[:,j]) / sqrt(32)
    {
        float acc = bq[t];
        for (int e = 0; e < EMBD; ++e) acc = fmaf(uL[e], Wq[e * EMBD + t], acc);
        scaleL[t] = acc * 0.17677669529663687f;
    }
    // C2: per-head max/min of ksum (exact softmax max via sign of scale)
    if (t < 64) {
        int h = t >> 3, seg = t & 7;
        float mx = -3.4e38f, mn = 3.4e38f;
        for (int n = seg * 25; n < seg * 25 + 25; ++n) {
            float s = ksumL[n * 8 + h];
            mx = fmaxf(mx, s); mn = fminf(mn, s);
        }
        mx = fmaxf(mx, __shfl_xor(mx, 1)); mn = fminf(mn, __shfl_xor(mn, 1));
        mx = fmaxf(mx, __shfl_xor(mx, 2)); mn = fminf(mn, __shfl_xor(mn, 2));
        mx = fmaxf(mx, __shfl_xor(mx, 4)); mn = fminf(mn, __shfl_xor(mn, 4));
        if (seg == 0) { maxkL[h] = mx; minkL[h] = mn; }
    }
    __syncthreads();
    // D1: per (h,qd): softmax max + 1/denominator
    {
        int h = t >> 5;
        float sc  = scaleL[t];
        float m   = (sc >= 0.f) ? sc * maxkL[h] : sc * minkL[h];
        float den = 0.f;
        for (int n = 0; n < NIT; ++n) den += __expf(sc * ksumL[n * 8 + h] - m);
        mL[t] = m; invdL[t] = 1.f / den;
    }
    __syncthreads();

    // per-thread W4 constants: lane owns hq = 16w + r16
    const int hq = 16 * w + r16, hh = hq >> 3, qm = hq & 7;
    float sc4[4], mm4[4], iv4[4];
    #pragma unroll
    for (int g = 0; g < 4; ++g) {
        int qi = hh * 32 + g * 8 + qm;
        sc4[g] = scaleL[qi]; mm4[g] = mL[qi]; iv4[g] = invdL[qi];
    }

    // ---------------- pass 2: T = W4 · (IT · Wv) ----------------
    unsigned short* Mt = (unsigned short*)mtRaw;       // [256][40] bf16
    f32x4 tacc[4];
    #pragma unroll
    for (int ct = 0; ct < 4; ++ct) tacc[ct] = (f32x4){0.f, 0.f, 0.f, 0.f};

    stage_write(sx, &itb[0][snl * 264 + seb]);
    __syncthreads();
    cur = 0;
    for (int c = 0; c < NC; ++c) {
        if (c + 1 < NC) stage_load(sx, idsL, item_table, c + 1, snl, seb);
        // W4 A-frag in-register: lane needs W4[hq][n = c*32 + 8*g4 + j]
        bf16x8 w4f;
        {
            int nb = c * 32 + 8 * g4;
            #pragma unroll
            for (int j = 0; j < 8; ++j) {
                int n = nb + j;
                float wv = 0.f;
                if (n < NIT) {
                    float s = ksumL[n * 8 + hh];
                    wv = __expf(fmaf(sc4[0], s, -mm4[0])) * iv4[0]
                       + __expf(fmaf(sc4[1], s, -mm4[1])) * iv4[1]
                       + __expf(fmaf(sc4[2], s, -mm4[2])) * iv4[2]
                       + __expf(fmaf(sc4[3], s, -mm4[3])) * iv4[3];
                }
                w4f[j] = (short)f2b(wv);
            }
        }
        // MFMA-1: M_chunk = IT_chunk · Wv  (write wave-private Mt rows, bf16)
        #pragma unroll
        for (int i = 0; i < 2; ++i) {
            f32x4 ma[4];
            #pragma unroll
            for (int ct = 0; ct < 4; ++ct) ma[ct] = (f32x4){0.f, 0.f, 0.f, 0.f};
            #pragma unroll
            for (int ks = 0; ks < 8; ++ks) {
                bf16x8 a = *(const bf16x8*)(&itb[cur][(16 * i + r16) * 264 + ks * 32 + g4 * 8]);
                #pragma unroll
                for (int ct = 0; ct < 4; ++ct)
                    ma[ct] = __builtin_amdgcn_mfma_f32_16x16x32_bf16(a, wvf[ct][ks], ma[ct], 0, 0, 0);
            }
            #pragma unroll
            for (int ct = 0; ct < 4; ++ct) {      // D rows=items, cols=c
                uint2 p; p.x = pack2(ma[ct][0], ma[ct][1]);
                        p.y = pack2(ma[ct][2], ma[ct][3]);
                *(uint2*)(Mt + (64 * w + 16 * ct + r16) * 40 + 16 * i + 4 * g4) = p;
            }
        }
        // MFMA-2: T += W4 · Mt  (Mt rows are wave-private: lgkmcnt orders RAW)
        #pragma unroll
        for (int ct = 0; ct < 4; ++ct) {
            bf16x8 bfr = *(const bf16x8*)(Mt + (64 * w + 16 * ct + r16) * 40 + 8 * g4);
            tacc[ct] = __builtin_amdgcn_mfma_f32_16x16x32_bf16(w4f, bfr, tacc[ct], 0, 0, 0);
        }
        if (c + 1 < NC) stage_write(sx, &itb[cur ^ 1][snl * 264 + seb]);
        __syncthreads();
        cur ^= 1;
    }

    // scatter T accumulators -> T3[h][qm][kd]; bijective over (w,ct,reg,lane)
    float* T3 = (float*)mtRaw;
    #pragma unroll
    for (int ct = 0; ct < 4; ++ct) {
        int cc = ct * 16 + r16;
        #pragma unroll
        for (int reg = 0; reg < 4; ++reg) {
            int row = 4 * g4 + reg;
            if ((cc >> 5) == (row >> 3)) {
                int h = 2 * w + (row >> 3), q2 = row & 7, kd = cc & 31;
                T3[h * 256 + q2 * 32 + kd] = tacc[ct][reg];
            }
        }
    }
    __syncthreads();
    {   // S[c=t] = biasS[kd] + sum_h T3
        float s = biasSL[t & 31];
        #pragma unroll
        for (int h = 0; h < 8; ++h) s += T3[h * 256 + t];
        SL[t] = s;
    }
    __syncthreads();
    {   // user_rep = S·Wo + 32*bo
        float acc = 32.f * bo[t];
        for (int cc = 0; cc < EMBD; ++cc) acc = fmaf(SL[cc], Wo[cc * EMBD + t], acc);
        user_rep[(long)b * EMBD + t] = acc;
    }
}

__global__ __launch_bounds__(256) void ut_mlp(
    const int*   __restrict__ user_id,
    const float* __restrict__ user_table,
    const float* __restrict__ user_rep,
    const float* __restrict__ W1, const float* __restrict__ b1,
    const float* __restrict__ W2, const float* __restrict__ b2,
    float*       __restrict__ out)
{
    __shared__ float X[8 * 512];
    __shared__ float Hs[8 * 1024];
    const int t  = threadIdx.x;
    const int b0 = blockIdx.x * 8;

    #pragma unroll
    for (int r = 0; r < 8; ++r) {
        X[r * 512 + t]       = user_table[(long)user_id[b0 + r] * EMBD + t];
        X[r * 512 + 256 + t] = user_rep[(long)(b0 + r) * EMBD + t];
    }
    __syncthreads();

    float acc[8][4];
    #pragma unroll
    for (int r = 0; r < 8; ++r) {
        #pragma unroll
        for (int k2 = 0; k2 < 4; ++k2) acc[r][k2] = b1[t + 256 * k2];
    }
    for (int e = 0; e < 512; ++e) {
        float w0 = W1[e * 1024 + t];
        float w1 = W1[e * 1024 + t + 256];
        float w2 = W1[e * 1024 + t + 512];
        float w3 = W1[e * 1024 + t + 768];
        #pragma unroll
        for (int r = 0; r < 8; ++r) {
            float x = X[r * 512 + e];
            acc[r][0] = fmaf(x, w0, acc[r][0]);
            acc[r][1] = fmaf(x, w1, acc[r][1]);
            acc[r][2] = fmaf(x, w2, acc[r][2]);
            acc[r][3] = fmaf(x, w3, acc[r][3]);
        }
    }
    #pragma unroll
    for (int r = 0; r < 8; ++r) {
        #pragma unroll
        for (int k2 = 0; k2 < 4; ++k2)
            Hs[r * 1024 + t + 256 * k2] = fmaxf(acc[r][k2], 0.f);
    }
    __syncthreads();

    float o[8];
    #pragma unroll
    for (int r = 0; r < 8; ++r) o[r] = b2[t];
    for (int kk = 0; kk < 1024; ++kk) {
        float wv = W2[kk * 256 + t];
        #pragma unroll
        for (int r = 0; r < 8; ++r) o[r] = fmaf(Hs[r * 1024 + kk], wv, o[r]);
    }
    #pragma unroll
    for (int r = 0; r < 8; ++r) out[(long)(b0 + r) * EMBD + t] = o[r];
}

extern "C" void kernel_launch(void* const* d_in, const int* in_sizes, int n_in,
                              void* d_out, int out_size, void* d_ws, size_t ws_size,
                              hipStream_t stream)
{
    (void)in_sizes; (void)n_in; (void)out_size; (void)ws_size;
    const int*   user_id    = (const int*)d_in[0];
    const int*   item_ids   = (const int*)d_in[1];
    const float* user_table = (const float*)d_in[2];
    const float* item_table = (const float*)d_in[3];
    const float* Wq = (const float*)d_in[4];
    const float* bq = (const float*)d_in[5];
    const float* Wk = (const float*)d_in[6];
    const float* bk = (const float*)d_in[7];
    const float* Wv = (const float*)d_in[8];
    const float* bv = (const float*)d_in[9];
    const float* Wo = (const float*)d_in[10];
    const float* bo = (const float*)d_in[11];
    const float* W1 = (const float*)d_in[12];
    const float* b1 = (const float*)d_in[13];
    const float* W2 = (const float*)d_in[14];
    const float* b2 = (const float*)d_in[15];

    float* user_rep = (float*)((char*)d_ws + UREP_OFF);

    ut_prep<<<273, 256, 0, stream>>>(Wk, bk, bv, Wv, d_ws);
    ut_main<<<BATCH, 256, 0, stream>>>(user_id, item_ids, user_table, item_table,
                                       Wq, bq, Wo, bo, d_ws, user_rep);
    ut_mlp<<<BATCH / 8, 256, 0, stream>>>(user_id, user_table, user_rep,
                                          W1, b1, W2, b2, (float*)d_out);
}